// Round 1
// baseline (1989.074 us; speedup 1.0000x reference)
//
#include <hip/hip_runtime.h>
#include <hip/hip_bf16.h>

// Problem constants (B=4, S=4096 -> T=16384 tokens)
#define T_TOK 16384
#define H_DIM 1024
#define I_DIM 3584
#define E_NUM 8
#define N13   7168    // 2*I: w1/w3 interleaved B rows (16-col groups)
#define TOTP  32768   // T_TOK * K(=2)

typedef __attribute__((ext_vector_type(8))) short s16x8;   // 8 bf16 (4 VGPRs) MFMA A/B frag
typedef __attribute__((ext_vector_type(4))) float f32x4;   // MFMA C/D frag
typedef unsigned short u16;

__device__ __forceinline__ u16 f2bf(float f) {
    union { float f; unsigned u; } c; c.f = f;
    unsigned r = c.u + 0x7fffu + ((c.u >> 16) & 1u);   // round-to-nearest-even
    return (u16)(r >> 16);
}

// async global->LDS, 16B per lane. LDS dest must be wave-uniform base + lane*16.
__device__ __forceinline__ void glds16(const u16* g, u16* l) {
    __builtin_amdgcn_global_load_lds(
        (const __attribute__((address_space(1))) unsigned int*)g,
        (__attribute__((address_space(3))) unsigned int*)l,
        16, 0, 0);
}

// ---------------- Router: fp32 logits, top-2, renorm weights; also emits x in bf16 ----------------
__global__ __launch_bounds__(64)
void router_k(const float* __restrict__ x, const float* __restrict__ gw,
              int* __restrict__ tk_idx, float* __restrict__ tk_w,
              int* __restrict__ counts, u16* __restrict__ xb)
{
    int t = blockIdx.x;
    int lane = threadIdx.x;
    const float* xr = x + (size_t)t * H_DIM;
    float xv[16];
#pragma unroll
    for (int j = 0; j < 16; j++) xv[j] = xr[j * 64 + lane];
    u16* xo = xb + (size_t)t * H_DIM;
#pragma unroll
    for (int j = 0; j < 16; j++) xo[j * 64 + lane] = f2bf(xv[j]);
    float lg[E_NUM];
#pragma unroll
    for (int e = 0; e < E_NUM; e++) {
        const float* g = gw + e * H_DIM;
        float s = 0.f;
#pragma unroll
        for (int j = 0; j < 16; j++) s += xv[j] * g[j * 64 + lane];
#pragma unroll
        for (int off = 32; off > 0; off >>= 1) s += __shfl_xor(s, off, 64);
        lg[e] = s;
    }
    if (lane == 0) {
        int i1 = 0; float m1 = lg[0];
#pragma unroll
        for (int e = 1; e < E_NUM; e++) if (lg[e] > m1) { m1 = lg[e]; i1 = e; }
        int i2 = -1; float m2 = -3.4e38f;
#pragma unroll
        for (int e = 0; e < E_NUM; e++) if (e != i1 && lg[e] > m2) { m2 = lg[e]; i2 = e; }
        float p1 = 1.f / (1.f + __expf(m2 - m1));   // renormalized top-2: denom cancels
        float p2 = 1.f - p1;
        tk_idx[t * 2]     = i1;
        tk_idx[t * 2 + 1] = i2;
        tk_w[t * 2]       = p1;
        tk_w[t * 2 + 1]   = p2;
        atomicAdd(&counts[i1], 1);
        atomicAdd(&counts[i2], 1);
    }
}

__global__ void offsets_k(const int* __restrict__ counts, int* __restrict__ offsets,
                          int* __restrict__ cursor)
{
    if (threadIdx.x == 0 && blockIdx.x == 0) {
        int acc = 0;
        for (int e = 0; e < E_NUM; e++) { offsets[e] = acc; cursor[e] = acc; acc += counts[e]; }
        offsets[E_NUM] = acc;
    }
}

__global__ __launch_bounds__(256)
void scatter_k(const int* __restrict__ tk_idx, const float* __restrict__ tk_w,
               int* __restrict__ cursor, int* __restrict__ perm, float* __restrict__ pw,
               int* __restrict__ posmap)
{
    int t = blockIdx.x * 256 + threadIdx.x;
    if (t >= T_TOK) return;
#pragma unroll
    for (int k = 0; k < 2; k++) {
        int e = tk_idx[t * 2 + k];
        int pos = atomicAdd(&cursor[e], 1);
        perm[pos] = t;
        pw[pos]   = tk_w[t * 2 + k];
        posmap[t * 2 + k] = pos;
    }
}

// ---------------- transpose-convert: src [E][M][N] fp32 -> dst [E][N][M] bf16 (for w2) ----------------
__global__ __launch_bounds__(256)
void tcvt_k(const float* __restrict__ src, u16* __restrict__ dst, int M, int N)
{
    size_t eo = (size_t)blockIdx.z * M * N;
    __shared__ u16 tl[32][33];
    int t = threadIdx.x;
    int r = t >> 3, c = (t & 7) * 4;
    int m0 = blockIdx.y * 32, n0 = blockIdx.x * 32;
    float4 v = *reinterpret_cast<const float4*>(src + eo + (size_t)(m0 + r) * N + n0 + c);
    tl[c + 0][r] = f2bf(v.x); tl[c + 1][r] = f2bf(v.y);
    tl[c + 2][r] = f2bf(v.z); tl[c + 3][r] = f2bf(v.w);
    __syncthreads();
    union { u16 s[4]; unsigned long long v; } u;
    u.s[0] = tl[r][c]; u.s[1] = tl[r][c + 1]; u.s[2] = tl[r][c + 2]; u.s[3] = tl[r][c + 3];
    *reinterpret_cast<unsigned long long*>(dst + eo + (size_t)(n0 + r) * M + m0 + c) = u.v;
}

// ---------------- transpose-convert w1/w3 -> interleaved w13t [E][7168][1024] bf16 ----------------
// B-row r: matrix = (r>>4)&1 (0=w1, 1=w3), col = (r>>5)*16 + (r&15).
__global__ __launch_bounds__(256)
void tcvt13_k(const float* __restrict__ src, u16* __restrict__ dst, int mat)
{
    size_t eo_s = (size_t)blockIdx.z * H_DIM * I_DIM;
    size_t eo_d = (size_t)blockIdx.z * (size_t)N13 * H_DIM;
    __shared__ u16 tl[32][33];
    int t = threadIdx.x;
    int r = t >> 3, c = (t & 7) * 4;
    int m0 = blockIdx.y * 32, n0 = blockIdx.x * 32;   // m over H rows, n over I cols
    float4 v = *reinterpret_cast<const float4*>(src + eo_s + (size_t)(m0 + r) * I_DIM + n0 + c);
    tl[c + 0][r] = f2bf(v.x); tl[c + 1][r] = f2bf(v.y);
    tl[c + 2][r] = f2bf(v.z); tl[c + 3][r] = f2bf(v.w);
    __syncthreads();
    union { u16 s[4]; unsigned long long v; } u;
    u.s[0] = tl[r][c]; u.s[1] = tl[r][c + 1]; u.s[2] = tl[r][c + 2]; u.s[3] = tl[r][c + 3];
    int ic = n0 + r;                                        // source I-col
    int orow = ((ic >> 4) << 5) + (mat << 4) + (ic & 15);   // interleaved B-row
    *reinterpret_cast<unsigned long long*>(dst + eo_d + (size_t)orow * H_DIM + m0 + c) = u.v;
}

// =================================================================================================
// GEMM template: 256x256 tile, BK=64, 512 threads = 8 waves (2M x 4N), 2-buffer LDS (128 KiB),
// counted vmcnt(8) across barriers (never drain in main loop), XOR LDS swizzle slot^=(row&7)
// applied as pre-swizzled GLOBAL source (global_load_lds dest stays linear) + swizzled ds_read.
// Per iteration: issue 8 glds (tile t+1) -> vmcnt(8) -> barrier -> 4 quadrant MFMA clusters
// (setprio around MFMA) -> barrier.
// =================================================================================================

// ---------------- GEMM1: hidden = pw * silu(x@w1) * (x@w3), grouped by expert -------------------
__global__ __launch_bounds__(512, 2)
void gemm1_k(const u16* __restrict__ xb, const u16* __restrict__ w13t,
             const int* __restrict__ offsets, const int* __restrict__ perm,
             const float* __restrict__ pw, u16* __restrict__ hidden)
{
    int e = blockIdx.z;
    int base = offsets[e];
    int cnt  = offsets[e + 1] - base;
    int m0 = blockIdx.y * 256;
    if (m0 >= cnt) return;
    int n0 = blockIdx.x * 256;

    __shared__ u16 As[2][256 * 64];   // 2 x 32 KB
    __shared__ u16 Bs[2][256 * 64];   // 2 x 32 KB

    int t = threadIdx.x;
    int lane = t & 63, wave = t >> 6;
    int wm = (wave >> 2) * 128;        // 0,128
    int wn = (wave & 3) * 64;          // 0,64,128,192
    int l15 = lane & 15, quad = lane >> 4;
    int x7 = l15 & 7;
    int s0 = (quad ^ x7) * 8;          // swizzled 16B-slot, kk=0 (u16 units)
    int s1 = ((4 + quad) ^ x7) * 8;    // kk=1

    // staging: thread t stages, for l in 0..3, tile-row ra=l*64+(t>>3), slot (t&7)^(ra&7)
    int sr = t >> 3;
    int ss = t & 7;
    const u16* aptr[4];
    const u16* bptr[4];
#pragma unroll
    for (int l = 0; l < 4; l++) {
        int ra = l * 64 + sr;
        int pr = m0 + ra; if (pr > cnt - 1) pr = cnt - 1;       // clamp: dup row, masked at epilogue
        aptr[l] = xb + (size_t)perm[base + pr] * H_DIM + (ss ^ (ra & 7)) * 8;
        bptr[l] = w13t + (size_t)e * N13 * H_DIM + (size_t)(n0 + ra) * H_DIM + (ss ^ (ra & 7)) * 8;
    }

    auto STAGE = [&](int buf, int k0) {
#pragma unroll
        for (int l = 0; l < 4; l++) glds16(aptr[l] + k0, &As[buf][l * 4096 + t * 8]);
#pragma unroll
        for (int l = 0; l < 4; l++) glds16(bptr[l] + k0, &Bs[buf][l * 4096 + t * 8]);
    };

    f32x4 acc[8][4] = {};   // wave output 128x64: [mh*4+i][nh*2+j]
    const int NT = H_DIM / 64;   // 16

    STAGE(0, 0);
    for (int kt = 0; kt < NT; ++kt) {
        int cur = kt & 1;
        if (kt + 1 < NT) {
            STAGE(cur ^ 1, (kt + 1) * 64);
            asm volatile("s_waitcnt vmcnt(8)" ::: "memory");   // tile kt landed; kt+1 in flight
        } else {
            asm volatile("s_waitcnt vmcnt(0)" ::: "memory");
        }
        __builtin_amdgcn_s_barrier();
        asm volatile("" ::: "memory");
        const u16* Ab = As[cur];
        const u16* Bb = Bs[cur];
#pragma unroll
        for (int mh = 0; mh < 2; mh++)
#pragma unroll
        for (int nh = 0; nh < 2; nh++) {
            s16x8 af[4][2], bf[2][2];
#pragma unroll
            for (int i = 0; i < 4; i++) {
                int row = wm + mh * 64 + i * 16 + l15;
                af[i][0] = *reinterpret_cast<const s16x8*>(Ab + row * 64 + s0);
                af[i][1] = *reinterpret_cast<const s16x8*>(Ab + row * 64 + s1);
            }
#pragma unroll
            for (int j = 0; j < 2; j++) {
                int row = wn + nh * 32 + j * 16 + l15;
                bf[j][0] = *reinterpret_cast<const s16x8*>(Bb + row * 64 + s0);
                bf[j][1] = *reinterpret_cast<const s16x8*>(Bb + row * 64 + s1);
            }
            __builtin_amdgcn_s_setprio(1);
#pragma unroll
            for (int j = 0; j < 2; j++)
#pragma unroll
            for (int i = 0; i < 4; i++)
#pragma unroll
            for (int kk = 0; kk < 2; kk++)
                acc[mh * 4 + i][nh * 2 + j] = __builtin_amdgcn_mfma_f32_16x16x32_bf16(
                    af[i][kk], bf[j][kk], acc[mh * 4 + i][nh * 2 + j], 0, 0, 0);
            __builtin_amdgcn_s_setprio(0);
        }
        __builtin_amdgcn_s_barrier();
        asm volatile("" ::: "memory");
    }

    // epilogue: j-pairs hold (z1,z3) for the same hidden col (interleaved w13t); fold pw here.
    int hc0 = (n0 + wn) >> 1;
#pragma unroll
    for (int i = 0; i < 8; i++) {
        int rowoff = (i >> 2) * 64 + (i & 3) * 16 + quad * 4;
#pragma unroll
        for (int r = 0; r < 4; r++) {
            int p = m0 + wm + rowoff + r;
            if (p < cnt) {
                float w = pw[base + p];
                u16* hrow = hidden + (size_t)(base + p) * I_DIM + hc0;
#pragma unroll
                for (int nh = 0; nh < 2; nh++) {
                    float z1 = acc[i][nh * 2 + 0][r];
                    float z3 = acc[i][nh * 2 + 1][r];
                    float hv = (z1 / (1.f + __expf(-z1))) * z3 * w;
                    hrow[nh * 16 + l15] = f2bf(hv);
                }
            }
        }
    }
}

// ---------------- GEMM2: ybuf[pos] = hidden[pos] @ w2 (grouped, plain stores) -------------------
__global__ __launch_bounds__(512, 2)
void gemm2_k(const u16* __restrict__ hidden, const u16* __restrict__ w2t,
             const int* __restrict__ offsets, float* __restrict__ ybuf)
{
    int e = blockIdx.z;
    int base = offsets[e];
    int cnt  = offsets[e + 1] - base;
    int m0 = blockIdx.y * 256;
    if (m0 >= cnt) return;
    int n0 = blockIdx.x * 256;

    __shared__ u16 As[2][256 * 64];
    __shared__ u16 Bs[2][256 * 64];

    int t = threadIdx.x;
    int lane = t & 63, wave = t >> 6;
    int wm = (wave >> 2) * 128;
    int wn = (wave & 3) * 64;
    int l15 = lane & 15, quad = lane >> 4;
    int x7 = l15 & 7;
    int s0 = (quad ^ x7) * 8;
    int s1 = ((4 + quad) ^ x7) * 8;

    int sr = t >> 3;
    int ss = t & 7;
    const u16* aptr[4];
    const u16* bptr[4];
    const u16* wb = w2t + (size_t)e * H_DIM * I_DIM;
#pragma unroll
    for (int l = 0; l < 4; l++) {
        int ra = l * 64 + sr;
        int pr = m0 + ra; if (pr > cnt - 1) pr = cnt - 1;
        aptr[l] = hidden + (size_t)(base + pr) * I_DIM + (ss ^ (ra & 7)) * 8;
        bptr[l] = wb + (size_t)(n0 + ra) * I_DIM + (ss ^ (ra & 7)) * 8;
    }

    auto STAGE = [&](int buf, int k0) {
#pragma unroll
        for (int l = 0; l < 4; l++) glds16(aptr[l] + k0, &As[buf][l * 4096 + t * 8]);
#pragma unroll
        for (int l = 0; l < 4; l++) glds16(bptr[l] + k0, &Bs[buf][l * 4096 + t * 8]);
    };

    f32x4 acc[8][4] = {};
    const int NT = I_DIM / 64;   // 56

    STAGE(0, 0);
    for (int kt = 0; kt < NT; ++kt) {
        int cur = kt & 1;
        if (kt + 1 < NT) {
            STAGE(cur ^ 1, (kt + 1) * 64);
            asm volatile("s_waitcnt vmcnt(8)" ::: "memory");
        } else {
            asm volatile("s_waitcnt vmcnt(0)" ::: "memory");
        }
        __builtin_amdgcn_s_barrier();
        asm volatile("" ::: "memory");
        const u16* Ab = As[cur];
        const u16* Bb = Bs[cur];
#pragma unroll
        for (int mh = 0; mh < 2; mh++)
#pragma unroll
        for (int nh = 0; nh < 2; nh++) {
            s16x8 af[4][2], bf[2][2];
#pragma unroll
            for (int i = 0; i < 4; i++) {
                int row = wm + mh * 64 + i * 16 + l15;
                af[i][0] = *reinterpret_cast<const s16x8*>(Ab + row * 64 + s0);
                af[i][1] = *reinterpret_cast<const s16x8*>(Ab + row * 64 + s1);
            }
#pragma unroll
            for (int j = 0; j < 2; j++) {
                int row = wn + nh * 32 + j * 16 + l15;
                bf[j][0] = *reinterpret_cast<const s16x8*>(Bb + row * 64 + s0);
                bf[j][1] = *reinterpret_cast<const s16x8*>(Bb + row * 64 + s1);
            }
            __builtin_amdgcn_s_setprio(1);
#pragma unroll
            for (int j = 0; j < 2; j++)
#pragma unroll
            for (int i = 0; i < 4; i++)
#pragma unroll
            for (int kk = 0; kk < 2; kk++)
                acc[mh * 4 + i][nh * 2 + j] = __builtin_amdgcn_mfma_f32_16x16x32_bf16(
                    af[i][kk], bf[j][kk], acc[mh * 4 + i][nh * 2 + j], 0, 0, 0);
            __builtin_amdgcn_s_setprio(0);
        }
        __builtin_amdgcn_s_barrier();
        asm volatile("" ::: "memory");
    }

#pragma unroll
    for (int i = 0; i < 8; i++) {
        int rowoff = (i >> 2) * 64 + (i & 3) * 16 + quad * 4;
#pragma unroll
        for (int r = 0; r < 4; r++) {
            int p = m0 + wm + rowoff + r;
            if (p < cnt) {
                float* orow = ybuf + (size_t)(base + p) * H_DIM + n0 + wn;
#pragma unroll
                for (int nh = 0; nh < 2; nh++)
#pragma unroll
                for (int j = 0; j < 2; j++)
                    orow[nh * 32 + j * 16 + l15] = acc[i][nh * 2 + j][r];
            }
        }
    }
}

// ---------------- Combine: out[t] = ybuf[pos_a] + ybuf[pos_b] ----------------
__global__ __launch_bounds__(256)
void combine_k(const float* __restrict__ ybuf, const int* __restrict__ posmap,
               float* __restrict__ out)
{
    int t = blockIdx.x;
    int c = threadIdx.x * 4;
    int pa = posmap[t * 2];
    int pb = posmap[t * 2 + 1];
    float4 a = *reinterpret_cast<const float4*>(ybuf + (size_t)pa * H_DIM + c);
    float4 b = *reinterpret_cast<const float4*>(ybuf + (size_t)pb * H_DIM + c);
    float4 o = make_float4(a.x + b.x, a.y + b.y, a.z + b.z, a.w + b.w);
    *reinterpret_cast<float4*>(out + (size_t)t * H_DIM + c) = o;
}

// ---------------- launch ----------------
extern "C" void kernel_launch(void* const* d_in, const int* in_sizes, int n_in,
                              void* d_out, int out_size, void* d_ws, size_t ws_size,
                              hipStream_t stream)
{
    (void)in_sizes; (void)n_in; (void)ws_size; (void)out_size;
    const float* x  = (const float*)d_in[0];   // [T, H]
    const float* gw = (const float*)d_in[1];   // [E, H]
    const float* w1 = (const float*)d_in[2];   // [E, H, I]
    const float* w3 = (const float*)d_in[3];   // [E, H, I]
    const float* w2 = (const float*)d_in[4];   // [E, I, H]
    float* out = (float*)d_out;

    char* ws = (char*)d_ws;
    int*   counts  = (int*)ws;
    int*   offsets = counts + 8;
    int*   cursor  = offsets + 9;
    int*   tk_idx  = (int*)(ws + 128);
    float* tk_w    = (float*)(ws + 128 + 131072);
    int*   perm    = (int*)(ws + 128 + 2 * 131072);
    float* pw      = (float*)(ws + 128 + 3 * 131072);
    int*   posmap  = (int*)(ws + 128 + 4 * 131072);
    u16* xb     = (u16*)(ws + (1 << 20));                       // [T,H] bf16, 32 MB
    u16* w13t   = xb + 16777216ull;                             // [E,7168,1024] bf16, 117.4 MB
    u16* w2t    = w13t + 58720256ull;                           // [E,H,I] bf16, 58.7 MB
    u16* hidden = w2t + 29360128ull;                            // [TOTP, I] bf16, 234.9 MB
    // ybuf (134 MB fp32) aliases xb+w13t (149 MB) — both dead after gemm1 completes
    float* ybuf = (float*)(ws + (1 << 20));

    hipMemsetAsync(ws, 0, 128, stream);
    router_k<<<T_TOK, 64, 0, stream>>>(x, gw, tk_idx, tk_w, counts, xb);
    offsets_k<<<1, 64, 0, stream>>>(counts, offsets, cursor);
    scatter_k<<<T_TOK / 256, 256, 0, stream>>>(tk_idx, tk_w, cursor, perm, pw, posmap);
    tcvt13_k<<<dim3(I_DIM / 32, H_DIM / 32, E_NUM), 256, 0, stream>>>(w1, w13t, 0);
    tcvt13_k<<<dim3(I_DIM / 32, H_DIM / 32, E_NUM), 256, 0, stream>>>(w3, w13t, 1);
    tcvt_k<<<dim3(H_DIM / 32, I_DIM / 32, E_NUM), 256, 0, stream>>>(w2, w2t, I_DIM, H_DIM);
    gemm1_k<<<dim3(N13 / 256, 64, E_NUM), 512, 0, stream>>>(xb, w13t, offsets, perm, pw, hidden);
    gemm2_k<<<dim3(H_DIM / 256, 64, E_NUM), 512, 0, stream>>>(hidden, w2t, offsets, ybuf);
    combine_k<<<T_TOK, 256, 0, stream>>>(ybuf, posmap, out);
}

// Round 2
// 1895.375 us; speedup vs baseline: 1.0494x; 1.0494x over previous
//
#include <hip/hip_runtime.h>
#include <hip/hip_bf16.h>

// Problem constants (B=4, S=4096 -> T=16384 tokens)
#define T_TOK 16384
#define H_DIM 1024
#define I_DIM 3584
#define E_NUM 8
#define N13   7168    // 2*I: w1/w3 interleaved B rows (16-col groups)
#define TOTP  32768   // T_TOK * K(=2)

typedef __attribute__((ext_vector_type(8))) short s16x8;   // 8 bf16 (4 VGPRs) MFMA A/B frag
typedef __attribute__((ext_vector_type(4))) float f32x4;   // MFMA C/D frag
typedef unsigned short u16;

__device__ __forceinline__ u16 f2bf(float f) {
    union { float f; unsigned u; } c; c.f = f;
    unsigned r = c.u + 0x7fffu + ((c.u >> 16) & 1u);   // round-to-nearest-even
    return (u16)(r >> 16);
}

// async global->LDS, 16B per lane. LDS dest must be wave-uniform base + lane*16.
__device__ __forceinline__ void glds16(const u16* g, u16* l) {
    __builtin_amdgcn_global_load_lds(
        (const __attribute__((address_space(1))) unsigned int*)g,
        (__attribute__((address_space(3))) unsigned int*)l,
        16, 0, 0);
}

// ---------------- Router: fp32 logits, top-2, renorm weights; also emits x in bf16 ----------------
__global__ __launch_bounds__(64)
void router_k(const float* __restrict__ x, const float* __restrict__ gw,
              int* __restrict__ tk_idx, float* __restrict__ tk_w,
              int* __restrict__ counts, u16* __restrict__ xb)
{
    int t = blockIdx.x;
    int lane = threadIdx.x;
    const float* xr = x + (size_t)t * H_DIM;
    float xv[16];
#pragma unroll
    for (int j = 0; j < 16; j++) xv[j] = xr[j * 64 + lane];
    u16* xo = xb + (size_t)t * H_DIM;
#pragma unroll
    for (int j = 0; j < 16; j++) xo[j * 64 + lane] = f2bf(xv[j]);
    float lg[E_NUM];
#pragma unroll
    for (int e = 0; e < E_NUM; e++) {
        const float* g = gw + e * H_DIM;
        float s = 0.f;
#pragma unroll
        for (int j = 0; j < 16; j++) s += xv[j] * g[j * 64 + lane];
#pragma unroll
        for (int off = 32; off > 0; off >>= 1) s += __shfl_xor(s, off, 64);
        lg[e] = s;
    }
    if (lane == 0) {
        int i1 = 0; float m1 = lg[0];
#pragma unroll
        for (int e = 1; e < E_NUM; e++) if (lg[e] > m1) { m1 = lg[e]; i1 = e; }
        int i2 = -1; float m2 = -3.4e38f;
#pragma unroll
        for (int e = 0; e < E_NUM; e++) if (e != i1 && lg[e] > m2) { m2 = lg[e]; i2 = e; }
        float p1 = 1.f / (1.f + __expf(m2 - m1));   // renormalized top-2: denom cancels
        float p2 = 1.f - p1;
        tk_idx[t * 2]     = i1;
        tk_idx[t * 2 + 1] = i2;
        tk_w[t * 2]       = p1;
        tk_w[t * 2 + 1]   = p2;
        atomicAdd(&counts[i1], 1);
        atomicAdd(&counts[i2], 1);
    }
}

__global__ void offsets_k(const int* __restrict__ counts, int* __restrict__ offsets,
                          int* __restrict__ cursor)
{
    if (threadIdx.x == 0 && blockIdx.x == 0) {
        int acc = 0;
        for (int e = 0; e < E_NUM; e++) { offsets[e] = acc; cursor[e] = acc; acc += counts[e]; }
        offsets[E_NUM] = acc;
    }
}

__global__ __launch_bounds__(256)
void scatter_k(const int* __restrict__ tk_idx, const float* __restrict__ tk_w,
               int* __restrict__ cursor, int* __restrict__ perm, float* __restrict__ pw,
               int* __restrict__ posmap)
{
    int t = blockIdx.x * 256 + threadIdx.x;
    if (t >= T_TOK) return;
#pragma unroll
    for (int k = 0; k < 2; k++) {
        int e = tk_idx[t * 2 + k];
        int pos = atomicAdd(&cursor[e], 1);
        perm[pos] = t;
        pw[pos]   = tk_w[t * 2 + k];
        posmap[t * 2 + k] = pos;
    }
}

// ---------------- wide transpose-convert: src [M][N] fp32 -> dst bf16, 128x32 tiles ----------------
// dst row = (mat<0) ? src-col : interleaved w13 row ((ic>>4)<<5)+(mat<<4)+(ic&15); dst col = src row.
// 256 B contiguous segments on both load and store side (vs 64 B in the old 32x32 version).
__global__ __launch_bounds__(256)
void tcvtw_k(const float* __restrict__ src, u16* __restrict__ dst,
             int M, int N, int mat, int dmul)
{
    size_t eo_s = (size_t)blockIdx.z * M * N;
    size_t eo_d = (size_t)blockIdx.z * (size_t)M * N * dmul;
    __shared__ u16 tl[32][136];   // [src-col][src-row], stride 272 B (16B-aligned rows)
    int t = threadIdx.x;
    int m0 = blockIdx.y * 128, n0 = blockIdx.x * 32;
    int lr = t >> 3, lc = (t & 7) * 4;
#pragma unroll
    for (int it = 0; it < 4; it++) {
        int mr = it * 32 + lr;
        float4 v = *reinterpret_cast<const float4*>(src + eo_s + (size_t)(m0 + mr) * N + n0 + lc);
        tl[lc + 0][mr] = f2bf(v.x); tl[lc + 1][mr] = f2bf(v.y);
        tl[lc + 2][mr] = f2bf(v.z); tl[lc + 3][mr] = f2bf(v.w);
    }
    __syncthreads();
    int sn = t >> 4, sm = (t & 15) * 8;
#pragma unroll
    for (int it = 0; it < 2; it++) {
        int nr = it * 16 + sn;
        int ic = n0 + nr;
        int orow = (mat < 0) ? ic : (((ic >> 4) << 5) + (mat << 4) + (ic & 15));
        s16x8 v = *reinterpret_cast<const s16x8*>(&tl[nr][sm]);
        *reinterpret_cast<s16x8*>(dst + eo_d + (size_t)orow * M + m0 + sm) = v;
    }
}

// =================================================================================================
// GEMM template: 256x256 tile, BK=64, 512 threads = 8 waves (2M x 4N), 2-buffer LDS (128 KiB),
// counted vmcnt(8) across barriers (never drain in main loop), XOR LDS swizzle slot^=(row&7)
// via pre-swizzled GLOBAL source (global_load_lds dest stays linear) + swizzled ds_read.
// R2 change: fragment loads HOISTED — all 16 A-frags loaded once per K-tile, B-frags once per
// nh-half => 24 ds_read_b128/wave/K-tile (was 48: every frag was read twice). LDS read volume
// was the critical path (384 KiB/CU/K-tile ~ 1536 cyc vs 614 cyc MFMA -> 40% ceiling, measured 32%).
// =================================================================================================

// ---------------- GEMM1: hidden = pw * silu(x@w1) * (x@w3), grouped by expert -------------------
__global__ __launch_bounds__(512, 2)
void gemm1_k(const u16* __restrict__ xb, const u16* __restrict__ w13t,
             const int* __restrict__ offsets, const int* __restrict__ perm,
             const float* __restrict__ pw, u16* __restrict__ hidden)
{
    int e = blockIdx.z;
    int base = offsets[e];
    int cnt  = offsets[e + 1] - base;
    int m0 = blockIdx.y * 256;
    if (m0 >= cnt) return;
    int n0 = blockIdx.x * 256;

    __shared__ u16 As[2][256 * 64];   // 2 x 32 KB
    __shared__ u16 Bs[2][256 * 64];   // 2 x 32 KB

    int t = threadIdx.x;
    int lane = t & 63, wave = t >> 6;
    int wm = (wave >> 2) * 128;        // 0,128
    int wn = (wave & 3) * 64;          // 0,64,128,192
    int l15 = lane & 15, quad = lane >> 4;
    int x7 = l15 & 7;
    int s0 = (quad ^ x7) * 8;          // swizzled 16B-slot, kk=0 (u16 units)
    int s1 = ((4 + quad) ^ x7) * 8;    // kk=1

    int sr = t >> 3;
    int ss = t & 7;
    const u16* aptr[4];
    const u16* bptr[4];
#pragma unroll
    for (int l = 0; l < 4; l++) {
        int ra = l * 64 + sr;
        int pr = m0 + ra; if (pr > cnt - 1) pr = cnt - 1;       // clamp: dup row, masked at epilogue
        aptr[l] = xb + (size_t)perm[base + pr] * H_DIM + (ss ^ (ra & 7)) * 8;
        bptr[l] = w13t + (size_t)e * N13 * H_DIM + (size_t)(n0 + ra) * H_DIM + (ss ^ (ra & 7)) * 8;
    }

    auto STAGE = [&](int buf, int k0) {
#pragma unroll
        for (int l = 0; l < 4; l++) glds16(aptr[l] + k0, &As[buf][l * 4096 + t * 8]);
#pragma unroll
        for (int l = 0; l < 4; l++) glds16(bptr[l] + k0, &Bs[buf][l * 4096 + t * 8]);
    };

    f32x4 acc[8][4] = {};   // wave output 128x64: [i2][nh*2+j]
    const int NT = H_DIM / 64;   // 16

    STAGE(0, 0);
    for (int kt = 0; kt < NT; ++kt) {
        int cur = kt & 1;
        if (kt + 1 < NT) {
            STAGE(cur ^ 1, (kt + 1) * 64);
            asm volatile("s_waitcnt vmcnt(8)" ::: "memory");   // tile kt landed; kt+1 in flight
        } else {
            asm volatile("s_waitcnt vmcnt(0)" ::: "memory");
        }
        __builtin_amdgcn_s_barrier();
        asm volatile("" ::: "memory");
        const u16* Ab = As[cur];
        const u16* Bb = Bs[cur];
        // hoisted A fragments: 16 ds_read_b128, each used by both nh clusters
        s16x8 af[8][2];
#pragma unroll
        for (int i2 = 0; i2 < 8; i2++) {
            int row = wm + i2 * 16 + l15;
            af[i2][0] = *reinterpret_cast<const s16x8*>(Ab + row * 64 + s0);
            af[i2][1] = *reinterpret_cast<const s16x8*>(Ab + row * 64 + s1);
        }
#pragma unroll
        for (int nh = 0; nh < 2; nh++) {
            s16x8 bf[2][2];
#pragma unroll
            for (int j = 0; j < 2; j++) {
                int row = wn + nh * 32 + j * 16 + l15;
                bf[j][0] = *reinterpret_cast<const s16x8*>(Bb + row * 64 + s0);
                bf[j][1] = *reinterpret_cast<const s16x8*>(Bb + row * 64 + s1);
            }
            __builtin_amdgcn_s_setprio(1);
#pragma unroll
            for (int kk = 0; kk < 2; kk++)
#pragma unroll
            for (int j = 0; j < 2; j++)
#pragma unroll
            for (int i2 = 0; i2 < 8; i2++)
                acc[i2][nh * 2 + j] = __builtin_amdgcn_mfma_f32_16x16x32_bf16(
                    af[i2][kk], bf[j][kk], acc[i2][nh * 2 + j], 0, 0, 0);
            __builtin_amdgcn_s_setprio(0);
        }
        __builtin_amdgcn_s_barrier();
        asm volatile("" ::: "memory");
    }

    // epilogue: j-pairs hold (z1,z3) for the same hidden col (interleaved w13t); fold pw here.
    int hc0 = (n0 + wn) >> 1;
#pragma unroll
    for (int i = 0; i < 8; i++) {
        int rowoff = (i >> 2) * 64 + (i & 3) * 16 + quad * 4;
#pragma unroll
        for (int r = 0; r < 4; r++) {
            int p = m0 + wm + rowoff + r;
            if (p < cnt) {
                float w = pw[base + p];
                u16* hrow = hidden + (size_t)(base + p) * I_DIM + hc0;
#pragma unroll
                for (int nh = 0; nh < 2; nh++) {
                    float z1 = acc[i][nh * 2 + 0][r];
                    float z3 = acc[i][nh * 2 + 1][r];
                    float hv = (z1 / (1.f + __expf(-z1))) * z3 * w;
                    hrow[nh * 16 + l15] = f2bf(hv);
                }
            }
        }
    }
}

// ---------------- GEMM2: ybuf[pos] = hidden[pos] @ w2 (grouped, plain stores) -------------------
__global__ __launch_bounds__(512, 2)
void gemm2_k(const u16* __restrict__ hidden, const u16* __restrict__ w2t,
             const int* __restrict__ offsets, float* __restrict__ ybuf)
{
    int e = blockIdx.z;
    int base = offsets[e];
    int cnt  = offsets[e + 1] - base;
    int m0 = blockIdx.y * 256;
    if (m0 >= cnt) return;
    int n0 = blockIdx.x * 256;

    __shared__ u16 As[2][256 * 64];
    __shared__ u16 Bs[2][256 * 64];

    int t = threadIdx.x;
    int lane = t & 63, wave = t >> 6;
    int wm = (wave >> 2) * 128;
    int wn = (wave & 3) * 64;
    int l15 = lane & 15, quad = lane >> 4;
    int x7 = l15 & 7;
    int s0 = (quad ^ x7) * 8;
    int s1 = ((4 + quad) ^ x7) * 8;

    int sr = t >> 3;
    int ss = t & 7;
    const u16* aptr[4];
    const u16* bptr[4];
    const u16* wb = w2t + (size_t)e * H_DIM * I_DIM;
#pragma unroll
    for (int l = 0; l < 4; l++) {
        int ra = l * 64 + sr;
        int pr = m0 + ra; if (pr > cnt - 1) pr = cnt - 1;
        aptr[l] = hidden + (size_t)(base + pr) * I_DIM + (ss ^ (ra & 7)) * 8;
        bptr[l] = wb + (size_t)(n0 + ra) * I_DIM + (ss ^ (ra & 7)) * 8;
    }

    auto STAGE = [&](int buf, int k0) {
#pragma unroll
        for (int l = 0; l < 4; l++) glds16(aptr[l] + k0, &As[buf][l * 4096 + t * 8]);
#pragma unroll
        for (int l = 0; l < 4; l++) glds16(bptr[l] + k0, &Bs[buf][l * 4096 + t * 8]);
    };

    f32x4 acc[8][4] = {};
    const int NT = I_DIM / 64;   // 56

    STAGE(0, 0);
    for (int kt = 0; kt < NT; ++kt) {
        int cur = kt & 1;
        if (kt + 1 < NT) {
            STAGE(cur ^ 1, (kt + 1) * 64);
            asm volatile("s_waitcnt vmcnt(8)" ::: "memory");
        } else {
            asm volatile("s_waitcnt vmcnt(0)" ::: "memory");
        }
        __builtin_amdgcn_s_barrier();
        asm volatile("" ::: "memory");
        const u16* Ab = As[cur];
        const u16* Bb = Bs[cur];
        s16x8 af[8][2];
#pragma unroll
        for (int i2 = 0; i2 < 8; i2++) {
            int row = wm + i2 * 16 + l15;
            af[i2][0] = *reinterpret_cast<const s16x8*>(Ab + row * 64 + s0);
            af[i2][1] = *reinterpret_cast<const s16x8*>(Ab + row * 64 + s1);
        }
#pragma unroll
        for (int nh = 0; nh < 2; nh++) {
            s16x8 bf[2][2];
#pragma unroll
            for (int j = 0; j < 2; j++) {
                int row = wn + nh * 32 + j * 16 + l15;
                bf[j][0] = *reinterpret_cast<const s16x8*>(Bb + row * 64 + s0);
                bf[j][1] = *reinterpret_cast<const s16x8*>(Bb + row * 64 + s1);
            }
            __builtin_amdgcn_s_setprio(1);
#pragma unroll
            for (int kk = 0; kk < 2; kk++)
#pragma unroll
            for (int j = 0; j < 2; j++)
#pragma unroll
            for (int i2 = 0; i2 < 8; i2++)
                acc[i2][nh * 2 + j] = __builtin_amdgcn_mfma_f32_16x16x32_bf16(
                    af[i2][kk], bf[j][kk], acc[i2][nh * 2 + j], 0, 0, 0);
            __builtin_amdgcn_s_setprio(0);
        }
        __builtin_amdgcn_s_barrier();
        asm volatile("" ::: "memory");
    }

#pragma unroll
    for (int i = 0; i < 8; i++) {
        int rowoff = (i >> 2) * 64 + (i & 3) * 16 + quad * 4;
#pragma unroll
        for (int r = 0; r < 4; r++) {
            int p = m0 + wm + rowoff + r;
            if (p < cnt) {
                float* orow = ybuf + (size_t)(base + p) * H_DIM + n0 + wn;
#pragma unroll
                for (int nh = 0; nh < 2; nh++)
#pragma unroll
                for (int j = 0; j < 2; j++)
                    orow[nh * 32 + j * 16 + l15] = acc[i][nh * 2 + j][r];
            }
        }
    }
}

// ---------------- Combine: out[t] = ybuf[pos_a] + ybuf[pos_b] ----------------
__global__ __launch_bounds__(256)
void combine_k(const float* __restrict__ ybuf, const int* __restrict__ posmap,
               float* __restrict__ out)
{
    int t = blockIdx.x;
    int c = threadIdx.x * 4;
    int pa = posmap[t * 2];
    int pb = posmap[t * 2 + 1];
    float4 a = *reinterpret_cast<const float4*>(ybuf + (size_t)pa * H_DIM + c);
    float4 b = *reinterpret_cast<const float4*>(ybuf + (size_t)pb * H_DIM + c);
    float4 o = make_float4(a.x + b.x, a.y + b.y, a.z + b.z, a.w + b.w);
    *reinterpret_cast<float4*>(out + (size_t)t * H_DIM + c) = o;
}

// ---------------- launch ----------------
extern "C" void kernel_launch(void* const* d_in, const int* in_sizes, int n_in,
                              void* d_out, int out_size, void* d_ws, size_t ws_size,
                              hipStream_t stream)
{
    (void)in_sizes; (void)n_in; (void)ws_size; (void)out_size;
    const float* x  = (const float*)d_in[0];   // [T, H]
    const float* gw = (const float*)d_in[1];   // [E, H]
    const float* w1 = (const float*)d_in[2];   // [E, H, I]
    const float* w3 = (const float*)d_in[3];   // [E, H, I]
    const float* w2 = (const float*)d_in[4];   // [E, I, H]
    float* out = (float*)d_out;

    char* ws = (char*)d_ws;
    int*   counts  = (int*)ws;
    int*   offsets = counts + 8;
    int*   cursor  = offsets + 9;
    int*   tk_idx  = (int*)(ws + 128);
    float* tk_w    = (float*)(ws + 128 + 131072);
    int*   perm    = (int*)(ws + 128 + 2 * 131072);
    float* pw      = (float*)(ws + 128 + 3 * 131072);
    int*   posmap  = (int*)(ws + 128 + 4 * 131072);
    u16* xb     = (u16*)(ws + (1 << 20));                       // [T,H] bf16, 32 MB
    u16* w13t   = xb + 16777216ull;                             // [E,7168,1024] bf16, 117.4 MB
    u16* w2t    = w13t + 58720256ull;                           // [E,H,I] bf16, 58.7 MB
    u16* hidden = w2t + 29360128ull;                            // [TOTP, I] bf16, 234.9 MB
    // ybuf (134 MB fp32) aliases xb+w13t (149 MB) — both dead after gemm1 completes
    float* ybuf = (float*)(ws + (1 << 20));

    hipMemsetAsync(ws, 0, 128, stream);
    router_k<<<T_TOK, 64, 0, stream>>>(x, gw, tk_idx, tk_w, counts, xb);
    offsets_k<<<1, 64, 0, stream>>>(counts, offsets, cursor);
    scatter_k<<<T_TOK / 256, 256, 0, stream>>>(tk_idx, tk_w, cursor, perm, pw, posmap);
    tcvtw_k<<<dim3(I_DIM / 32, H_DIM / 128, E_NUM), 256, 0, stream>>>(w1, w13t, H_DIM, I_DIM, 0, 2);
    tcvtw_k<<<dim3(I_DIM / 32, H_DIM / 128, E_NUM), 256, 0, stream>>>(w3, w13t, H_DIM, I_DIM, 1, 2);
    tcvtw_k<<<dim3(H_DIM / 32, I_DIM / 128, E_NUM), 256, 0, stream>>>(w2, w2t, I_DIM, H_DIM, -1, 1);
    gemm1_k<<<dim3(N13 / 256, 64, E_NUM), 512, 0, stream>>>(xb, w13t, offsets, perm, pw, hidden);
    gemm2_k<<<dim3(H_DIM / 256, 64, E_NUM), 512, 0, stream>>>(hidden, w2t, offsets, ybuf);
    combine_k<<<T_TOK, 256, 0, stream>>>(ybuf, posmap, out);
}

// Round 3
// 1795.263 us; speedup vs baseline: 1.1080x; 1.0558x over previous
//
#include <hip/hip_runtime.h>
#include <hip/hip_bf16.h>

// Problem constants (B=4, S=4096 -> T=16384 tokens)
#define T_TOK 16384
#define H_DIM 1024
#define I_DIM 3584
#define E_NUM 8
#define N13   7168    // 2*I: w1/w3 interleaved B rows (16-col groups)
#define TOTP  32768   // T_TOK * K(=2)

typedef __attribute__((ext_vector_type(8))) short s16x8;   // 8 bf16 (4 VGPRs) MFMA A/B frag
typedef __attribute__((ext_vector_type(4))) float f32x4;   // MFMA C/D frag
typedef unsigned short u16;

#define BAR()    asm volatile("s_barrier" ::: "memory")
#define WAITL()  asm volatile("s_waitcnt lgkmcnt(0)" ::: "memory")
#define WAITV4() asm volatile("s_waitcnt vmcnt(4)" ::: "memory")
#define WAITV0() asm volatile("s_waitcnt vmcnt(0)" ::: "memory")

__device__ __forceinline__ u16 f2bf(float f) {
    union { float f; unsigned u; } c; c.f = f;
    unsigned r = c.u + 0x7fffu + ((c.u >> 16) & 1u);   // round-to-nearest-even
    return (u16)(r >> 16);
}

// async global->LDS, 16B per lane. LDS dest must be wave-uniform base + lane*16.
__device__ __forceinline__ void glds16(const u16* g, u16* l) {
    __builtin_amdgcn_global_load_lds(
        (const __attribute__((address_space(1))) unsigned int*)g,
        (__attribute__((address_space(3))) unsigned int*)l,
        16, 0, 0);
}

// ---------------- Router: fp32 logits, top-2, renorm weights; also emits x in bf16 ----------------
__global__ __launch_bounds__(64)
void router_k(const float* __restrict__ x, const float* __restrict__ gw,
              int* __restrict__ tk_idx, float* __restrict__ tk_w,
              int* __restrict__ counts, u16* __restrict__ xb)
{
    int t = blockIdx.x;
    int lane = threadIdx.x;
    const float* xr = x + (size_t)t * H_DIM;
    float xv[16];
#pragma unroll
    for (int j = 0; j < 16; j++) xv[j] = xr[j * 64 + lane];
    u16* xo = xb + (size_t)t * H_DIM;
#pragma unroll
    for (int j = 0; j < 16; j++) xo[j * 64 + lane] = f2bf(xv[j]);
    float lg[E_NUM];
#pragma unroll
    for (int e = 0; e < E_NUM; e++) {
        const float* g = gw + e * H_DIM;
        float s = 0.f;
#pragma unroll
        for (int j = 0; j < 16; j++) s += xv[j] * g[j * 64 + lane];
#pragma unroll
        for (int off = 32; off > 0; off >>= 1) s += __shfl_xor(s, off, 64);
        lg[e] = s;
    }
    if (lane == 0) {
        int i1 = 0; float m1 = lg[0];
#pragma unroll
        for (int e = 1; e < E_NUM; e++) if (lg[e] > m1) { m1 = lg[e]; i1 = e; }
        int i2 = -1; float m2 = -3.4e38f;
#pragma unroll
        for (int e = 0; e < E_NUM; e++) if (e != i1 && lg[e] > m2) { m2 = lg[e]; i2 = e; }
        float p1 = 1.f / (1.f + __expf(m2 - m1));   // renormalized top-2: denom cancels
        float p2 = 1.f - p1;
        tk_idx[t * 2]     = i1;
        tk_idx[t * 2 + 1] = i2;
        tk_w[t * 2]       = p1;
        tk_w[t * 2 + 1]   = p2;
        atomicAdd(&counts[i1], 1);
        atomicAdd(&counts[i2], 1);
    }
}

__global__ void offsets_k(const int* __restrict__ counts, int* __restrict__ offsets,
                          int* __restrict__ cursor)
{
    if (threadIdx.x == 0 && blockIdx.x == 0) {
        int acc = 0;
        for (int e = 0; e < E_NUM; e++) { offsets[e] = acc; cursor[e] = acc; acc += counts[e]; }
        offsets[E_NUM] = acc;
    }
}

__global__ __launch_bounds__(256)
void scatter_k(const int* __restrict__ tk_idx, const float* __restrict__ tk_w,
               int* __restrict__ cursor, int* __restrict__ perm, float* __restrict__ pw,
               int* __restrict__ posmap)
{
    int t = blockIdx.x * 256 + threadIdx.x;
    if (t >= T_TOK) return;
#pragma unroll
    for (int k = 0; k < 2; k++) {
        int e = tk_idx[t * 2 + k];
        int pos = atomicAdd(&cursor[e], 1);
        perm[pos] = t;
        pw[pos]   = tk_w[t * 2 + k];
        posmap[t * 2 + k] = pos;
    }
}

// ---------------- wide transpose-convert: src [M][N] fp32 -> dst bf16, 128x32 tiles ----------------
__global__ __launch_bounds__(256)
void tcvtw_k(const float* __restrict__ src, u16* __restrict__ dst,
             int M, int N, int mat, int dmul)
{
    size_t eo_s = (size_t)blockIdx.z * M * N;
    size_t eo_d = (size_t)blockIdx.z * (size_t)M * N * dmul;
    __shared__ u16 tl[32][136];   // [src-col][src-row], 16B-aligned rows
    int t = threadIdx.x;
    int m0 = blockIdx.y * 128, n0 = blockIdx.x * 32;
    int lr = t >> 3, lc = (t & 7) * 4;
#pragma unroll
    for (int it = 0; it < 4; it++) {
        int mr = it * 32 + lr;
        float4 v = *reinterpret_cast<const float4*>(src + eo_s + (size_t)(m0 + mr) * N + n0 + lc);
        tl[lc + 0][mr] = f2bf(v.x); tl[lc + 1][mr] = f2bf(v.y);
        tl[lc + 2][mr] = f2bf(v.z); tl[lc + 3][mr] = f2bf(v.w);
    }
    __syncthreads();
    int sn = t >> 4, sm = (t & 15) * 8;
#pragma unroll
    for (int it = 0; it < 2; it++) {
        int nr = it * 16 + sn;
        int ic = n0 + nr;
        int orow = (mat < 0) ? ic : (((ic >> 4) << 5) + (mat << 4) + (ic & 15));
        s16x8 v = *reinterpret_cast<const s16x8*>(&tl[nr][sm]);
        *reinterpret_cast<s16x8*>(dst + eo_d + (size_t)orow * M + m0 + sm) = v;
    }
}

// =================================================================================================
// 8-PHASE GEMM (m201-style port): 256x256 tile, BK=64, 512 thr = 8 waves (2Mx4N), LDS 128 KiB.
// Slot0 = even K-tiles, slot1 = odd. Per iteration (2 K-tiles), 8 phases, each:
//   {<=10 ds_read || stage 1 half-tile (2 glds)} -> barrier -> lgkmcnt(0) -> 16 MFMA (setprio) -> barrier
// Stage order: B1h0,B1h1 (k=2it+1), A0h0,A0h1 (k=2it+2), B0h0,B0h1 (k=2it+2), A1h0,A1h1 (k=2it+3).
// vmcnt(4) ONLY at phases 4 & 8 (drains exactly the 8 loads the next read-phase needs; 4 stay
// in flight). Ledger verified: every slot staged only after the barrier closing its last read.
// =================================================================================================

// ---------------- GEMM1: hidden = pw * silu(x@w1) * (x@w3), grouped by expert -------------------
__global__ __launch_bounds__(512, 2)
void gemm1_k(const u16* __restrict__ xb, const u16* __restrict__ w13t,
             const int* __restrict__ offsets, const int* __restrict__ perm,
             const float* __restrict__ pw, u16* __restrict__ hidden)
{
    int e = blockIdx.z;
    int base = offsets[e];
    int cnt  = offsets[e + 1] - base;
    int m0 = blockIdx.y * 256;
    if (m0 >= cnt) return;
    int n0 = blockIdx.x * 256;

    __shared__ u16 As[2][16384];   // 2 x 32 KB (one K-tile of A each)
    __shared__ u16 Bs[2][16384];   // 2 x 32 KB

    int t = threadIdx.x;
    int lane = t & 63, wave = t >> 6;
    int wm = (wave >> 2) * 128;        // 0,128
    int wn = (wave & 3) * 64;          // 0,64,128,192
    int l15 = lane & 15, quad = lane >> 4;
    int x7 = l15 & 7;
    int sl0 = (quad ^ x7) * 8;         // swizzled 16B-slot, kk=0 (u16 units)
    int sl1 = ((4 + quad) ^ x7) * 8;   // kk=1

    int sr = t >> 3;
    int ss = t & 7;
    const u16* aptr[4];
    const u16* bptr[4];
#pragma unroll
    for (int l = 0; l < 4; l++) {
        int ra = l * 64 + sr;
        int pr = m0 + ra; if (pr > cnt - 1) pr = cnt - 1;       // clamp: dup row, masked at epilogue
        aptr[l] = xb + (size_t)perm[base + pr] * H_DIM + (ss ^ (ra & 7)) * 8;
        bptr[l] = w13t + (size_t)e * N13 * H_DIM + (size_t)(n0 + ra) * H_DIM + (ss ^ (ra & 7)) * 8;
    }

    u16* A0l = &As[0][0]; u16* A1l = &As[1][0];
    u16* B0l = &Bs[0][0]; u16* B1l = &Bs[1][0];

    auto STG = [&](u16* lbase, const u16* const* gptr, int h, int koff) {
        glds16(gptr[2 * h]     + koff, lbase + (2 * h)     * 4096 + t * 8);
        glds16(gptr[2 * h + 1] + koff, lbase + (2 * h + 1) * 4096 + t * 8);
    };
    auto RDA = [&](const u16* Ab, s16x8* af, int kksel) {
#pragma unroll
        for (int i2 = 0; i2 < 8; i2++) {
            int row = wm + i2 * 16 + l15;
            af[i2] = *reinterpret_cast<const s16x8*>(Ab + row * 64 + (kksel ? sl1 : sl0));
        }
    };
    auto RDB = [&](const u16* Bb, s16x8* bf, int nh, int kksel) {
#pragma unroll
        for (int j = 0; j < 2; j++) {
            int row = wn + nh * 32 + j * 16 + l15;
            bf[j] = *reinterpret_cast<const s16x8*>(Bb + row * 64 + (kksel ? sl1 : sl0));
        }
    };

    f32x4 acc[8][4] = {};   // wave output 128x64: [i2][nh*2+j]
    auto MF = [&](const s16x8* af, const s16x8* bf, int nh) {
        __builtin_amdgcn_s_setprio(1);
#pragma unroll
        for (int j = 0; j < 2; j++)
#pragma unroll
        for (int i2 = 0; i2 < 8; i2++)
            acc[i2][nh * 2 + j] = __builtin_amdgcn_mfma_f32_16x16x32_bf16(
                af[i2], bf[j], acc[i2][nh * 2 + j], 0, 0, 0);
        __builtin_amdgcn_s_setprio(0);
    };

    const int NT = H_DIM / 64;   // 16
    const int NTI = NT / 2;      // 8

    // prologue: A0,B0 @k=0 (8 loads), A1 @k=1 (4 loads); drain first 8, keep 4 in flight
    STG(A0l, aptr, 0, 0);  STG(A0l, aptr, 1, 0);
    STG(B0l, bptr, 0, 0);  STG(B0l, bptr, 1, 0);
    STG(A1l, aptr, 0, 64); STG(A1l, aptr, 1, 64);
    WAITV4(); BAR();

    for (int it = 0; it < NTI; ++it) {
        int ko1 = (2 * it + 1) * 64;
        int ko2 = (2 * it + 2 < NT) ? (2 * it + 2) * 64 : 0;   // tail: dummy re-stage, never read
        int ko3 = (2 * it + 3 < NT) ? (2 * it + 3) * 64 : 0;
        s16x8 af0[8], af1[8], bfa[2], bfb[2];
        // ph1: reads k=2it (slot0) kk0; stage B1h0 (k=2it+1)
        RDA(A0l, af0, 0); RDB(B0l, bfa, 0, 0); STG(B1l, bptr, 0, ko1);
        BAR(); WAITL(); MF(af0, bfa, 0); BAR();
        // ph2: kk1; stage B1h1
        RDA(A0l, af1, 1); RDB(B0l, bfb, 0, 1); STG(B1l, bptr, 1, ko1);
        BAR(); WAITL(); MF(af1, bfb, 0); BAR();
        // ph3: bf(nh1,kk0); stage A0h0 (k=2it+2) — A slot0 fully read after ph2's barrier
        RDB(B0l, bfa, 1, 0); STG(A0l, aptr, 0, ko2);
        BAR(); WAITL(); MF(af0, bfa, 1); BAR();
        // ph4: bf(nh1,kk1); stage A0h1; vmcnt(4) protects ph5 reads (A1 prev ph7/8 + B1 ph1/2)
        RDB(B0l, bfb, 1, 1); STG(A0l, aptr, 1, ko2);
        BAR(); WAITL(); MF(af1, bfb, 1); WAITV4(); BAR();
        // ph5: reads k=2it+1 (slot1) kk0; stage B0h0 (k=2it+2) — B slot0 fully read after ph4
        RDA(A1l, af0, 0); RDB(B1l, bfa, 0, 0); STG(B0l, bptr, 0, ko2);
        BAR(); WAITL(); MF(af0, bfa, 0); BAR();
        // ph6: kk1; stage B0h1
        RDA(A1l, af1, 1); RDB(B1l, bfb, 0, 1); STG(B0l, bptr, 1, ko2);
        BAR(); WAITL(); MF(af1, bfb, 0); BAR();
        // ph7: bf(nh1,kk0); stage A1h0 (k=2it+3) — A slot1 fully read after ph6
        RDB(B1l, bfa, 1, 0); STG(A1l, aptr, 0, ko3);
        BAR(); WAITL(); MF(af0, bfa, 1); BAR();
        // ph8: bf(nh1,kk1); stage A1h1; vmcnt(4) protects next-iter ph1 (A0 ph3/4 + B0 ph5/6)
        RDB(B1l, bfb, 1, 1); STG(A1l, aptr, 1, ko3);
        BAR(); WAITL(); MF(af1, bfb, 1); WAITV4(); BAR();
    }
    WAITV0();   // retire tail dummy stages before epilogue/endpgm

    // epilogue: j-pairs hold (z1,z3) for the same hidden col (interleaved w13t); fold pw here.
    int hc0 = (n0 + wn) >> 1;
#pragma unroll
    for (int i = 0; i < 8; i++) {
        int rowoff = (i >> 2) * 64 + (i & 3) * 16 + quad * 4;
#pragma unroll
        for (int r = 0; r < 4; r++) {
            int p = m0 + wm + rowoff + r;
            if (p < cnt) {
                float w = pw[base + p];
                u16* hrow = hidden + (size_t)(base + p) * I_DIM + hc0;
#pragma unroll
                for (int nh = 0; nh < 2; nh++) {
                    float z1 = acc[i][nh * 2 + 0][r];
                    float z3 = acc[i][nh * 2 + 1][r];
                    float hv = (z1 / (1.f + __expf(-z1))) * z3 * w;
                    hrow[nh * 16 + l15] = f2bf(hv);
                }
            }
        }
    }
}

// ---------------- GEMM2: ybuf[pos] = hidden[pos] @ w2 (grouped, plain stores) -------------------
__global__ __launch_bounds__(512, 2)
void gemm2_k(const u16* __restrict__ hidden, const u16* __restrict__ w2t,
             const int* __restrict__ offsets, float* __restrict__ ybuf)
{
    int e = blockIdx.z;
    int base = offsets[e];
    int cnt  = offsets[e + 1] - base;
    int m0 = blockIdx.y * 256;
    if (m0 >= cnt) return;
    int n0 = blockIdx.x * 256;

    __shared__ u16 As[2][16384];
    __shared__ u16 Bs[2][16384];

    int t = threadIdx.x;
    int lane = t & 63, wave = t >> 6;
    int wm = (wave >> 2) * 128;
    int wn = (wave & 3) * 64;
    int l15 = lane & 15, quad = lane >> 4;
    int x7 = l15 & 7;
    int sl0 = (quad ^ x7) * 8;
    int sl1 = ((4 + quad) ^ x7) * 8;

    int sr = t >> 3;
    int ss = t & 7;
    const u16* aptr[4];
    const u16* bptr[4];
    const u16* wb = w2t + (size_t)e * H_DIM * I_DIM;
#pragma unroll
    for (int l = 0; l < 4; l++) {
        int ra = l * 64 + sr;
        int pr = m0 + ra; if (pr > cnt - 1) pr = cnt - 1;
        aptr[l] = hidden + (size_t)(base + pr) * I_DIM + (ss ^ (ra & 7)) * 8;
        bptr[l] = wb + (size_t)(n0 + ra) * I_DIM + (ss ^ (ra & 7)) * 8;
    }

    u16* A0l = &As[0][0]; u16* A1l = &As[1][0];
    u16* B0l = &Bs[0][0]; u16* B1l = &Bs[1][0];

    auto STG = [&](u16* lbase, const u16* const* gptr, int h, int koff) {
        glds16(gptr[2 * h]     + koff, lbase + (2 * h)     * 4096 + t * 8);
        glds16(gptr[2 * h + 1] + koff, lbase + (2 * h + 1) * 4096 + t * 8);
    };
    auto RDA = [&](const u16* Ab, s16x8* af, int kksel) {
#pragma unroll
        for (int i2 = 0; i2 < 8; i2++) {
            int row = wm + i2 * 16 + l15;
            af[i2] = *reinterpret_cast<const s16x8*>(Ab + row * 64 + (kksel ? sl1 : sl0));
        }
    };
    auto RDB = [&](const u16* Bb, s16x8* bf, int nh, int kksel) {
#pragma unroll
        for (int j = 0; j < 2; j++) {
            int row = wn + nh * 32 + j * 16 + l15;
            bf[j] = *reinterpret_cast<const s16x8*>(Bb + row * 64 + (kksel ? sl1 : sl0));
        }
    };

    f32x4 acc[8][4] = {};
    auto MF = [&](const s16x8* af, const s16x8* bf, int nh) {
        __builtin_amdgcn_s_setprio(1);
#pragma unroll
        for (int j = 0; j < 2; j++)
#pragma unroll
        for (int i2 = 0; i2 < 8; i2++)
            acc[i2][nh * 2 + j] = __builtin_amdgcn_mfma_f32_16x16x32_bf16(
                af[i2], bf[j], acc[i2][nh * 2 + j], 0, 0, 0);
        __builtin_amdgcn_s_setprio(0);
    };

    const int NT = I_DIM / 64;   // 56
    const int NTI = NT / 2;      // 28

    STG(A0l, aptr, 0, 0);  STG(A0l, aptr, 1, 0);
    STG(B0l, bptr, 0, 0);  STG(B0l, bptr, 1, 0);
    STG(A1l, aptr, 0, 64); STG(A1l, aptr, 1, 64);
    WAITV4(); BAR();

    for (int it = 0; it < NTI; ++it) {
        int ko1 = (2 * it + 1) * 64;
        int ko2 = (2 * it + 2 < NT) ? (2 * it + 2) * 64 : 0;
        int ko3 = (2 * it + 3 < NT) ? (2 * it + 3) * 64 : 0;
        s16x8 af0[8], af1[8], bfa[2], bfb[2];
        RDA(A0l, af0, 0); RDB(B0l, bfa, 0, 0); STG(B1l, bptr, 0, ko1);
        BAR(); WAITL(); MF(af0, bfa, 0); BAR();
        RDA(A0l, af1, 1); RDB(B0l, bfb, 0, 1); STG(B1l, bptr, 1, ko1);
        BAR(); WAITL(); MF(af1, bfb, 0); BAR();
        RDB(B0l, bfa, 1, 0); STG(A0l, aptr, 0, ko2);
        BAR(); WAITL(); MF(af0, bfa, 1); BAR();
        RDB(B0l, bfb, 1, 1); STG(A0l, aptr, 1, ko2);
        BAR(); WAITL(); MF(af1, bfb, 1); WAITV4(); BAR();
        RDA(A1l, af0, 0); RDB(B1l, bfa, 0, 0); STG(B0l, bptr, 0, ko2);
        BAR(); WAITL(); MF(af0, bfa, 0); BAR();
        RDA(A1l, af1, 1); RDB(B1l, bfb, 0, 1); STG(B0l, bptr, 1, ko2);
        BAR(); WAITL(); MF(af1, bfb, 0); BAR();
        RDB(B1l, bfa, 1, 0); STG(A1l, aptr, 0, ko3);
        BAR(); WAITL(); MF(af0, bfa, 1); BAR();
        RDB(B1l, bfb, 1, 1); STG(A1l, aptr, 1, ko3);
        BAR(); WAITL(); MF(af1, bfb, 1); WAITV4(); BAR();
    }
    WAITV0();

#pragma unroll
    for (int i = 0; i < 8; i++) {
        int rowoff = (i >> 2) * 64 + (i & 3) * 16 + quad * 4;
#pragma unroll
        for (int r = 0; r < 4; r++) {
            int p = m0 + wm + rowoff + r;
            if (p < cnt) {
                float* orow = ybuf + (size_t)(base + p) * H_DIM + n0 + wn;
#pragma unroll
                for (int nh = 0; nh < 2; nh++)
#pragma unroll
                for (int j = 0; j < 2; j++)
                    orow[nh * 32 + j * 16 + l15] = acc[i][nh * 2 + j][r];
            }
        }
    }
}

// ---------------- Combine: out[t] = ybuf[pos_a] + ybuf[pos_b] ----------------
__global__ __launch_bounds__(256)
void combine_k(const float* __restrict__ ybuf, const int* __restrict__ posmap,
               float* __restrict__ out)
{
    int t = blockIdx.x;
    int c = threadIdx.x * 4;
    int pa = posmap[t * 2];
    int pb = posmap[t * 2 + 1];
    float4 a = *reinterpret_cast<const float4*>(ybuf + (size_t)pa * H_DIM + c);
    float4 b = *reinterpret_cast<const float4*>(ybuf + (size_t)pb * H_DIM + c);
    float4 o = make_float4(a.x + b.x, a.y + b.y, a.z + b.z, a.w + b.w);
    *reinterpret_cast<float4*>(out + (size_t)t * H_DIM + c) = o;
}

// ---------------- launch ----------------
extern "C" void kernel_launch(void* const* d_in, const int* in_sizes, int n_in,
                              void* d_out, int out_size, void* d_ws, size_t ws_size,
                              hipStream_t stream)
{
    (void)in_sizes; (void)n_in; (void)ws_size; (void)out_size;
    const float* x  = (const float*)d_in[0];   // [T, H]
    const float* gw = (const float*)d_in[1];   // [E, H]
    const float* w1 = (const float*)d_in[2];   // [E, H, I]
    const float* w3 = (const float*)d_in[3];   // [E, H, I]
    const float* w2 = (const float*)d_in[4];   // [E, I, H]
    float* out = (float*)d_out;

    char* ws = (char*)d_ws;
    int*   counts  = (int*)ws;
    int*   offsets = counts + 8;
    int*   cursor  = offsets + 9;
    int*   tk_idx  = (int*)(ws + 128);
    float* tk_w    = (float*)(ws + 128 + 131072);
    int*   perm    = (int*)(ws + 128 + 2 * 131072);
    float* pw      = (float*)(ws + 128 + 3 * 131072);
    int*   posmap  = (int*)(ws + 128 + 4 * 131072);
    u16* xb     = (u16*)(ws + (1 << 20));                       // [T,H] bf16, 32 MB
    u16* w13t   = xb + 16777216ull;                             // [E,7168,1024] bf16, 117.4 MB
    u16* w2t    = w13t + 58720256ull;                           // [E,H,I] bf16, 58.7 MB
    u16* hidden = w2t + 29360128ull;                            // [TOTP, I] bf16, 234.9 MB
    // ybuf (134 MB fp32) aliases xb+w13t (149 MB) — both dead after gemm1 completes
    float* ybuf = (float*)(ws + (1 << 20));

    hipMemsetAsync(ws, 0, 128, stream);
    router_k<<<T_TOK, 64, 0, stream>>>(x, gw, tk_idx, tk_w, counts, xb);
    offsets_k<<<1, 64, 0, stream>>>(counts, offsets, cursor);
    scatter_k<<<T_TOK / 256, 256, 0, stream>>>(tk_idx, tk_w, cursor, perm, pw, posmap);
    tcvtw_k<<<dim3(I_DIM / 32, H_DIM / 128, E_NUM), 256, 0, stream>>>(w1, w13t, H_DIM, I_DIM, 0, 2);
    tcvtw_k<<<dim3(I_DIM / 32, H_DIM / 128, E_NUM), 256, 0, stream>>>(w3, w13t, H_DIM, I_DIM, 1, 2);
    tcvtw_k<<<dim3(H_DIM / 32, I_DIM / 128, E_NUM), 256, 0, stream>>>(w2, w2t, I_DIM, H_DIM, -1, 1);
    gemm1_k<<<dim3(N13 / 256, 64, E_NUM), 512, 0, stream>>>(xb, w13t, offsets, perm, pw, hidden);
    gemm2_k<<<dim3(H_DIM / 256, 64, E_NUM), 512, 0, stream>>>(hidden, w2t, offsets, ybuf);
    combine_k<<<T_TOK, 256, 0, stream>>>(ybuf, posmap, out);
}